// Round 4
// baseline (1284.121 us; speedup 1.0000x reference)
//
#include <hip/hip_runtime.h>
#include <cstdint>

typedef unsigned short u16;
typedef unsigned int u32;
typedef __bf16 bf16x8 __attribute__((ext_vector_type(8)));
typedef float f32x4 __attribute__((ext_vector_type(4)));
typedef unsigned short u16x8 __attribute__((ext_vector_type(8)));
typedef unsigned short u16x4 __attribute__((ext_vector_type(4)));

#define BM 128
#define BN 128
#define BK 32    // per-plane K depth; main loop processes 2 planes (K=64) per barrier pair
#define PL (BM * BK)   // plane stride in elements (4096)
#define CL 16     // scan chunk length
#define NC 256    // chunks per channel (CL*NC = 4096 = L)
#define DI 2048   // d_inner
#define DM 1024   // d_model
#define LSEQ 4096

__device__ __forceinline__ float bf2f(u16 u) {
    union { uint32_t i; float f; } v; v.i = ((uint32_t)u) << 16; return v.f;
}
__device__ __forceinline__ u16 f2bf(float f) {
    union { float f; uint32_t i; } v; v.f = f;
    uint32_t r = v.i + 0x7fffu + ((v.i >> 16) & 1u);
    return (u16)(r >> 16);
}

// async global->LDS, 16B per lane; LDS dst = base + lane*16 (wave-uniform base)
__device__ __forceinline__ void gl_lds16(const u16* g, u16* l) {
    __builtin_amdgcn_global_load_lds(
        (const __attribute__((address_space(1))) u32*)g,
        (__attribute__((address_space(3))) u32*)l, 16, 0, 0);
}

// ---------------------------------------------------------------------------
// f32 -> bf16 cast (vectorized x8)
// ---------------------------------------------------------------------------
__global__ __launch_bounds__(256)
void cast_f2b(const float* __restrict__ src, u16* __restrict__ dst, long n)
{
    long i = ((long)blockIdx.x * 256 + threadIdx.x) * 8;
    if (i >= n) return;
    float4 v0 = *(const float4*)(src + i);
    float4 v1 = *(const float4*)(src + i + 4);
    u16x8 o;
    o[0] = f2bf(v0.x); o[1] = f2bf(v0.y); o[2] = f2bf(v0.z); o[3] = f2bf(v0.w);
    o[4] = f2bf(v1.x); o[5] = f2bf(v1.y); o[6] = f2bf(v1.z); o[7] = f2bf(v1.w);
    *(u16x8*)(dst + i) = o;
}

// all 5 weight casts in one launch (segments are multiples of 8 elements)
__global__ __launch_bounds__(256)
void cast_weights(const float* __restrict__ Wi, const float* __restrict__ Wdt,
                  const float* __restrict__ WB, const float* __restrict__ WC,
                  const float* __restrict__ Wo,
                  u16* __restrict__ Wi_b, u16* __restrict__ Wcat_b,
                  u16* __restrict__ Wo_b)
{
    const long nWi = (long)2 * DI * DM;
    const long nWp = (long)DI * DI;
    long i = ((long)blockIdx.x * 256 + threadIdx.x) * 8;
    const float* src; u16* dst; long off;
    if (i < nWi)                  { src = Wi;  dst = Wi_b;            off = i; }
    else if (i < nWi + nWp)       { src = Wdt; dst = Wcat_b;          off = i - nWi; }
    else if (i < nWi + 2 * nWp)   { src = WB;  dst = Wcat_b + nWp;    off = i - nWi - nWp; }
    else if (i < nWi + 3 * nWp)   { src = WC;  dst = Wcat_b + 2*nWp;  off = i - nWi - 2*nWp; }
    else                          { src = Wo;  dst = Wo_b;            off = i - nWi - 3*nWp; }
    float4 v0 = *(const float4*)(src + off);
    float4 v1 = *(const float4*)(src + off + 4);
    u16x8 o;
    o[0] = f2bf(v0.x); o[1] = f2bf(v0.y); o[2] = f2bf(v0.z); o[3] = f2bf(v0.w);
    o[4] = f2bf(v1.x); o[5] = f2bf(v1.y); o[6] = f2bf(v1.z); o[7] = f2bf(v1.w);
    *(u16x8*)(dst + off) = o;
}

// ---------------------------------------------------------------------------
// GEMM (m97-style, K-unrolled x2): C[M,N] = A[M,K] * W[N,K]^T, bf16, fp32 acc.
// LDS: two independent 32-col planes per matrix (verified BK=32 swizzle kept
// per plane). Each iteration stages K=64 (8 x global_load_lds) then runs
// 32 MFMA per wave -> half the barrier/vmcnt-drain events of BK=32.
// Staging swizzle: row r holds global 16B-chunk c at slot (c + (r>>1)) & 3.
// NOTE: XCD block swizzle was tried (R3) and REGRESSED (FETCH 366->768 MB):
// on a 128-Mtile x 48-Ntile grid it serializes each XCD over a full M-band,
// destroying B-panel reuse. Default round-robin mapping is better here.
// EPI 0: in_proj  N=4096, split -> x1(ob0), z(ob1)          [bf16]
// EPI 1: fused proj N=6144, group nc>>11: 0 softplus+bias->dt(ob0),
//        1 sigmoid*xc(auxb)->u(ob1), 2 tanh->Ct(ob2)        [bf16]
// EPI 2: out_proj N=1024 -> f32 (outf)
// ---------------------------------------------------------------------------
template<int EPI>
__device__ __forceinline__ void gemm_body(
             const u16* __restrict__ A, const u16* __restrict__ W, int K,
             const float* __restrict__ auxf, const u16* __restrict__ auxb,
             u16* __restrict__ ob0, u16* __restrict__ ob1,
             u16* __restrict__ ob2, float* __restrict__ outf)
{
    __shared__ __align__(16) u16 As[2 * BM * BK];   // 16 KB: two planes
    __shared__ __align__(16) u16 Bs[2 * BN * BK];   // 16 KB

    const int t    = threadIdx.x;
    const int lane = t & 63;
    const int w    = t >> 6;
    const int quad = lane >> 4;
    const int l16  = lane & 15;
    const int wm   = w >> 1, wn = w & 1;
    const long m0  = (long)blockIdx.y * BM;
    const long n0  = (long)blockIdx.x * BN;

    // ---- staging lane constants ----
    // inst q covers rows q*16..q*16+15; lane i -> row q*16 + (i>>2), slot i&3
    // global chunk for this slot: cg = ((i&3) - ((i>>3)&3)) & 3
    const int rr = lane >> 2;
    const int cg = ((lane & 3) - ((lane >> 3) & 3)) & 3;

    const u16* gA0 = A + (size_t)(m0 + (2 * w)     * 16 + rr) * K + cg * 8;
    const u16* gA1 = A + (size_t)(m0 + (2 * w + 1) * 16 + rr) * K + cg * 8;
    const u16* gB0 = W + (size_t)(n0 + (2 * w)     * 16 + rr) * K + cg * 8;
    const u16* gB1 = W + (size_t)(n0 + (2 * w + 1) * 16 + rr) * K + cg * 8;

    u16* lA0 = As + (2 * w)     * 512;
    u16* lA1 = As + (2 * w + 1) * 512;
    u16* lB0 = Bs + (2 * w)     * 512;
    u16* lB1 = Bs + (2 * w + 1) * 512;

    // ---- fragment read constants ----
    const int slotr = (quad + (l16 >> 1)) & 3;
    const u16* rdA = As + (wm * 64 + l16) * 32 + slotr * 8;
    const u16* rdB = Bs + (wn * 64 + l16) * 32 + slotr * 8;

    f32x4 acc[4][4];
#pragma unroll
    for (int i = 0; i < 4; ++i)
#pragma unroll
        for (int j = 0; j < 4; ++j)
            acc[i][j] = (f32x4){0.f, 0.f, 0.f, 0.f};

    for (int k0 = 0; k0 < K; k0 += 2 * BK) {
        __syncthreads();                    // prev-iter LDS reads done
        gl_lds16(gA0 + k0, lA0);
        gl_lds16(gA1 + k0, lA1);
        gl_lds16(gA0 + k0 + BK, lA0 + PL);
        gl_lds16(gA1 + k0 + BK, lA1 + PL);
        gl_lds16(gB0 + k0, lB0);
        gl_lds16(gB1 + k0, lB1);
        gl_lds16(gB0 + k0 + BK, lB0 + PL);
        gl_lds16(gB1 + k0 + BK, lB1 + PL);
        __syncthreads();                    // DMA drained

#pragma unroll
        for (int kk = 0; kk < 2; ++kk) {
            const u16* pA = rdA + kk * PL;
            const u16* pB = rdB + kk * PL;
            bf16x8 af[4], bfr[4];
#pragma unroll
            for (int fi = 0; fi < 4; ++fi)
                af[fi] = *(const bf16x8*)(pA + fi * 512);
#pragma unroll
            for (int fj = 0; fj < 4; ++fj)
                bfr[fj] = *(const bf16x8*)(pB + fj * 512);
#pragma unroll
            for (int i = 0; i < 4; ++i)
#pragma unroll
                for (int j = 0; j < 4; ++j)
                    acc[i][j] = __builtin_amdgcn_mfma_f32_16x16x32_bf16(af[i], bfr[j], acc[i][j], 0, 0, 0);
        }
    }

    // epilogue: C/D layout col=lane&15, row=quad*4+reg  [m89/m91-verified]
#pragma unroll
    for (int i = 0; i < 4; ++i) {
#pragma unroll
        for (int j = 0; j < 4; ++j) {
            const long nc = n0 + wn * 64 + j * 16 + l16;
#pragma unroll
            for (int rg = 0; rg < 4; ++rg) {
                const long mr = m0 + wm * 64 + i * 16 + quad * 4 + rg;
                float v = acc[i][j][rg];
                if (EPI == 0) {
                    if (nc < DI) ob0[mr * DI + nc] = f2bf(v);
                    else         ob1[mr * DI + (nc - DI)] = f2bf(v);
                } else if (EPI == 1) {
                    const int  g   = (int)(nc >> 11);   // block-uniform
                    const long col = nc & (DI - 1);
                    if (g == 0) {
                        v += auxf[col];
                        float sp = (v > 20.f) ? v : log1pf(expf(v));
                        ob0[mr * DI + col] = f2bf(sp);
                    } else if (g == 1) {
                        float bt  = 1.f / (1.f + expf(-v));
                        float xcv = bf2f(auxb[mr * DI + col]);
                        ob1[mr * DI + col] = f2bf(xcv * bt);
                    } else {
                        ob2[mr * DI + col] = f2bf(tanhf(v));
                    }
                } else {
                    outf[mr * DM + nc] = v;
                }
            }
        }
    }
}

// distinct names so rocprof's top-5 decomposes the GEMM share
__global__ __launch_bounds__(256, 4)
void gemm_in(const u16* __restrict__ A, const u16* __restrict__ W, int K,
             u16* __restrict__ ob0, u16* __restrict__ ob1)
{
    gemm_body<0>(A, W, K, nullptr, nullptr, ob0, ob1, nullptr, nullptr);
}
__global__ __launch_bounds__(256, 4)
void gemm_dbc(const u16* __restrict__ A, const u16* __restrict__ W, int K,
              const float* __restrict__ auxf, const u16* __restrict__ auxb,
              u16* __restrict__ ob0, u16* __restrict__ ob1, u16* __restrict__ ob2)
{
    gemm_body<1>(A, W, K, auxf, auxb, ob0, ob1, ob2, nullptr);
}
__global__ __launch_bounds__(256, 4)
void gemm_out(const u16* __restrict__ A, const u16* __restrict__ W, int K,
              float* __restrict__ outf)
{
    gemm_body<2>(A, W, K, nullptr, nullptr, nullptr, nullptr, nullptr, outf);
}

// ---------------------------------------------------------------------------
// depthwise causal conv1d (k=4) + bias + silu : x1[nb,L,D](bf16) -> xc (bf16)
// one block per (b,l) row; 256 threads x 8 channels = DI; 16B row loads
// ---------------------------------------------------------------------------
__global__ __launch_bounds__(256)
void conv_silu(const u16* __restrict__ x1, const float* __restrict__ Wc,
               const float* __restrict__ bc, u16* __restrict__ xc)
{
    const long bl = blockIdx.x;             // b*L + l
    const int  l  = (int)(bl & (LSEQ - 1));
    const int  d0 = threadIdx.x * 8;
    const size_t base = (size_t)bl * DI + d0;

    float acc[8];
    {
        float4 b0 = *(const float4*)(bc + d0);
        float4 b1 = *(const float4*)(bc + d0 + 4);
        acc[0] = b0.x; acc[1] = b0.y; acc[2] = b0.z; acc[3] = b0.w;
        acc[4] = b1.x; acc[5] = b1.y; acc[6] = b1.z; acc[7] = b1.w;
    }
    float wv[8][4];
#pragma unroll
    for (int v = 0; v < 8; ++v) {
        float4 t = *(const float4*)(Wc + (size_t)(d0 + v) * 4);
        wv[v][0] = t.x; wv[v][1] = t.y; wv[v][2] = t.z; wv[v][3] = t.w;
    }

#pragma unroll
    for (int tp = 0; tp < 4; ++tp) {
        const int ls = l - 3 + tp;          // uniform per block
        if (ls >= 0) {
            u16x8 vx = *(const u16x8*)(x1 + base + (long)(tp - 3) * DI);
#pragma unroll
            for (int v = 0; v < 8; ++v)
                acc[v] += bf2f(vx[v]) * wv[v][tp];
        }
    }
    u16x8 o;
#pragma unroll
    for (int v = 0; v < 8; ++v) {
        float s = acc[v] / (1.f + expf(-acc[v]));   // silu
        o[v] = f2bf(s);
    }
    *(u16x8*)(xc + base) = o;
}

// ---------------------------------------------------------------------------
// scan (h_l = exp(la_l)*h_{l-1} + beta_l), chunked 3-pass.
// 4 channels/thread, grid (2, nb, NC) = 2048 blocks (100% wave capacity),
// prefetch depth 2 on all streams for memory-level parallelism.
// NOTE: prefetch may read up to 32B past a big buffer's end (into the next
// allocated buffer) on the trailing chunks — value discarded, always in-ws.
// ---------------------------------------------------------------------------
__global__ __launch_bounds__(256)
void scan_a(const u16* __restrict__ dt, const u16* __restrict__ u,
            const float* __restrict__ A_log,
            float* __restrict__ sumlog, float* __restrict__ hend, int nbD)
{
    const int d0 = (blockIdx.x * 256 + threadIdx.x) * 4;   // 2*256*4 = DI
    const int b  = blockIdx.y;
    const int c  = blockIdx.z;
    float Ad[4];
    {
        float4 a = *(const float4*)(A_log + d0);
        Ad[0] = -expf(a.x); Ad[1] = -expf(a.y); Ad[2] = -expf(a.z); Ad[3] = -expf(a.w);
    }
    size_t base = ((size_t)b * LSEQ + (size_t)c * CL) * DI + d0;

    float pu[4], sl[4], h[4];
    if (c == 0) {
#pragma unroll
        for (int v = 0; v < 4; ++v) pu[v] = 0.f;
    } else {
        u16x4 vp = *(const u16x4*)(u + base - DI);
#pragma unroll
        for (int v = 0; v < 4; ++v) pu[v] = bf2f(vp[v]);
    }
#pragma unroll
    for (int v = 0; v < 4; ++v) { sl[v] = 0.f; h[v] = 0.f; }

    u16x4 d_0 = *(const u16x4*)(dt + base);
    u16x4 u_0 = *(const u16x4*)(u  + base);
    u16x4 d_1 = *(const u16x4*)(dt + base + DI);
    u16x4 u_1 = *(const u16x4*)(u  + base + DI);
    for (int s = 0; s < CL; ++s) {
        u16x4 d_2 = *(const u16x4*)(dt + base + 2 * DI);
        u16x4 u_2 = *(const u16x4*)(u  + base + 2 * DI);
#pragma unroll
        for (int v = 0; v < 4; ++v) {
            float dtv = bf2f(d_0[v]);
            float uv  = bf2f(u_0[v]);
            float la  = fminf(fmaxf(Ad[v] * dtv, -10.f), -1e-4f);
            sl[v] += la;
            h[v] = expf(la) * h[v] + dtv * 0.5f * (pu[v] + uv);
            pu[v] = uv;
        }
        d_0 = d_1; u_0 = u_1; d_1 = d_2; u_1 = u_2;
        base += DI;
    }
    const size_t chn = (size_t)c * nbD + b * DI + d0;
    *(float4*)(sumlog + chn) = (float4){sl[0], sl[1], sl[2], sl[3]};
    *(float4*)(hend   + chn) = (float4){h[0], h[1], h[2], h[3]};
}

// 128-thread blocks (64 blocks for nbD=8192); unroll-by-8 with hoisted loads
// and batched exp so the ~700-cycle load latency is paid NC/8 times, not NC.
__global__ __launch_bounds__(128)
void scan_b(const float* __restrict__ sumlog, const float* __restrict__ hend,
            float* __restrict__ hin, int nbD)
{
    const int chn = blockIdx.x * 128 + threadIdx.x;   // 0..nbD-1
    float carry = 0.f;
    for (int c0 = 0; c0 < NC; c0 += 8) {
        float sl[8], he[8];
#pragma unroll
        for (int k = 0; k < 8; ++k) {
            sl[k] = sumlog[(size_t)(c0 + k) * nbD + chn];
            he[k] = hend  [(size_t)(c0 + k) * nbD + chn];
        }
        float e[8];
#pragma unroll
        for (int k = 0; k < 8; ++k) e[k] = expf(sl[k]);
#pragma unroll
        for (int k = 0; k < 8; ++k) {
            hin[(size_t)(c0 + k) * nbD + chn] = carry;
            carry = e[k] * carry + he[k];
        }
    }
}

__global__ __launch_bounds__(256)
void scan_c(const u16* __restrict__ dt, const u16* __restrict__ u,
            const float* __restrict__ A_log, const float* __restrict__ hin,
            const u16* __restrict__ Ct, const u16* __restrict__ z,
            u16* __restrict__ y, int nbD)
{
    const int d0 = (blockIdx.x * 256 + threadIdx.x) * 4;
    const int b  = blockIdx.y;
    const int c  = blockIdx.z;
    float Ad[4];
    {
        float4 a = *(const float4*)(A_log + d0);
        Ad[0] = -expf(a.x); Ad[1] = -expf(a.y); Ad[2] = -expf(a.z); Ad[3] = -expf(a.w);
    }
    size_t base = ((size_t)b * LSEQ + (size_t)c * CL) * DI + d0;
    const size_t chn = (size_t)c * nbD + b * DI + d0;

    float h[4], pu[4];
    {
        float4 h4 = *(const float4*)(hin + chn);
        h[0] = h4.x; h[1] = h4.y; h[2] = h4.z; h[3] = h4.w;
    }
    if (c == 0) {
#pragma unroll
        for (int v = 0; v < 4; ++v) pu[v] = 0.f;
    } else {
        u16x4 vp = *(const u16x4*)(u + base - DI);
#pragma unroll
        for (int v = 0; v < 4; ++v) pu[v] = bf2f(vp[v]);
    }

    u16x4 d_0 = *(const u16x4*)(dt + base);
    u16x4 u_0 = *(const u16x4*)(u  + base);
    u16x4 c_0 = *(const u16x4*)(Ct + base);
    u16x4 z_0 = *(const u16x4*)(z  + base);
    u16x4 d_1 = *(const u16x4*)(dt + base + DI);
    u16x4 u_1 = *(const u16x4*)(u  + base + DI);
    u16x4 c_1 = *(const u16x4*)(Ct + base + DI);
    u16x4 z_1 = *(const u16x4*)(z  + base + DI);
    for (int s = 0; s < CL; ++s) {
        u16x4 d_2 = *(const u16x4*)(dt + base + 2 * DI);
        u16x4 u_2 = *(const u16x4*)(u  + base + 2 * DI);
        u16x4 c_2 = *(const u16x4*)(Ct + base + 2 * DI);
        u16x4 z_2 = *(const u16x4*)(z  + base + 2 * DI);
        u16x4 o;
#pragma unroll
        for (int v = 0; v < 4; ++v) {
            float dtv = bf2f(d_0[v]);
            float uv  = bf2f(u_0[v]);
            float la  = fminf(fmaxf(Ad[v] * dtv, -10.f), -1e-4f);
            h[v] = expf(la) * h[v] + dtv * 0.5f * (pu[v] + uv);
            pu[v] = uv;
            float ct = bf2f(c_0[v]);
            float zv = bf2f(z_0[v]);
            float sz = zv / (1.f + expf(-zv));   // silu(z)
            o[v] = f2bf(h[v] * ct * sz);
        }
        *(u16x4*)(y + base) = o;
        d_0 = d_1; u_0 = u_1; c_0 = c_1; z_0 = z_1;
        d_1 = d_2; u_1 = u_2; c_1 = c_2; z_1 = z_2;
        base += DI;
    }
}

// ---------------------------------------------------------------------------
struct WeightsB {   // bf16 casts of the big weights (in ws)
    const u16 *Wi, *Wcat, *Wo;   // Wcat = [Wdt; WB; WC], 6144 x 2048
};
struct SmallF {     // small f32 inputs consumed directly
    const float *Wconv, *bconv, *bdt, *A_log;
};

static void run_pipeline(int nb, const float* x, float* out, char* ws,
                         const WeightsB& wb, const SmallF& sf, hipStream_t stream)
{
    const int Mrows = nb * LSEQ;
    const size_t nE = (size_t)Mrows * DI;    // elements per big buffer
    const size_t nX = (size_t)Mrows * DM;
    const int nbD = nb * DI;

    char* p = ws;
    u16* b0 = (u16*)p; p += nE * 2;   // x1, then dt
    u16* b1 = (u16*)p; p += nE * 2;   // z
    u16* b2 = (u16*)p; p += nE * 2;   // xc  (first half doubles as xb; scan
                                      //      smalls live here after EPI1 GEMM)
    u16* b3 = (u16*)p; p += nE * 2;   // u
    u16* b4 = (u16*)p; p += nE * 2;   // Ct, then y (in-place in scan_c)

    u16* xb = b2;                       // x cast; dead before conv writes xc
    u16* x1 = b0; u16* z = b1; u16* xc = b2;
    u16* dt = b0; u16* u  = b3; u16* Ct = b4; u16* y = b4;

    // scan chunk summaries: xc/b2 is dead after the EPI1 GEMM consumes it
    // (3 * nbD * NC * 4 bytes = 25 MB @ nb=4  <<  nE*2 = 67 MB)
    float* sumlog = (float*)b2;
    float* hend   = sumlog + (size_t)nbD * NC;
    float* hin    = hend   + (size_t)nbD * NC;

    dim3 blk(256);

    // 0) cast activations input (into xc's buffer — released before conv)
    cast_f2b<<<dim3((unsigned)(nX / 2048)), blk, 0, stream>>>(x, xb, (long)nX);

    // 1) in_proj: xz = x @ Wi^T -> (x1, z)
    gemm_in<<<dim3(2 * DI / BN, Mrows / BM), blk, 0, stream>>>(
        xb, wb.Wi, DM, x1, z);

    // 2) causal depthwise conv + silu (overwrites xb region)
    conv_silu<<<dim3((unsigned)Mrows), blk, 0, stream>>>(x1, sf.Wconv, sf.bconv, xc);

    // 3) fused dt/B/C projection (one N=6144 GEMM); dt overwrites x1
    gemm_dbc<<<dim3(3 * DI / BN, Mrows / BM), blk, 0, stream>>>(
        xc, wb.Wcat, DI, sf.bdt, xc, dt, u, Ct);

    // 4) chunked scan + fuse y = h * Ct * silu(z); y overwrites Ct in-place
    scan_a<<<dim3(2, nb, NC), blk, 0, stream>>>(dt, u, sf.A_log, sumlog, hend, nbD);
    scan_b<<<dim3(nbD / 128), dim3(128), 0, stream>>>(sumlog, hend, hin, nbD);
    scan_c<<<dim3(2, nb, NC), blk, 0, stream>>>(dt, u, sf.A_log, hin, Ct, z, y, nbD);

    // 5) out_proj -> out (f32)
    gemm_out<<<dim3(DM / BN, Mrows / BM), blk, 0, stream>>>(
        y, wb.Wo, DI, out);
}

extern "C" void kernel_launch(void* const* d_in, const int* in_sizes, int n_in,
                              void* d_out, int out_size, void* d_ws, size_t ws_size,
                              hipStream_t stream)
{
    const float* x     = (const float*)d_in[0];
    const float* Wi    = (const float*)d_in[1];
    const float* Wconv = (const float*)d_in[2];
    const float* bconv = (const float*)d_in[3];
    const float* Wdt   = (const float*)d_in[4];
    const float* bdt   = (const float*)d_in[5];
    const float* WB    = (const float*)d_in[6];
    const float* WC    = (const float*)d_in[7];
    const float* Wo    = (const float*)d_in[8];
    const float* A_log = (const float*)d_in[9];

    const size_t nWi = (size_t)2 * DI * DM;   // 4.19M
    const size_t nWp = (size_t)DI * DI;       // 4.19M
    const size_t nWo = (size_t)DM * DI;       // 2.10M

    // weight casts live at the END of ws (shared by all paths)
    const size_t wbytes = (nWi + 3 * nWp + nWo) * 2;
    char* q = (char*)d_ws + ws_size - wbytes;
    u16* Wi_b   = (u16*)q; q += nWi * 2;
    u16* Wcat_b = (u16*)q; q += 3 * nWp * 2;   // [Wdt; WB; WC]
    u16* Wo_b   = (u16*)q; q += nWo * 2;

    dim3 blk(256);
    {
        const long nW = (long)(nWi + 3 * nWp + nWo);   // 18.9M, /8/256 = 9216 blocks
        cast_weights<<<dim3((unsigned)(nW / 2048)), blk, 0, stream>>>(
            Wi, Wdt, WB, WC, Wo, Wi_b, Wcat_b, Wo_b);
    }

    WeightsB wb{Wi_b, Wcat_b, Wo_b};
    SmallF   sf{Wconv, bconv, bdt, A_log};

    // big-buffer need for nb batches (xb and scan smalls aliased into xc):
    auto need = [&](int nb) -> size_t {
        size_t nE = (size_t)nb * LSEQ * DI;
        return 5 * nE * 2;
    };

    if (ws_size >= need(4) + wbytes) {
        run_pipeline(4, x, (float*)d_out, (char*)d_ws, wb, sf, stream);
    } else if (ws_size >= need(2) + wbytes) {
        for (int b = 0; b < 4; b += 2)
            run_pipeline(2, x + (size_t)b * LSEQ * DM,
                         (float*)d_out + (size_t)b * LSEQ * DM,
                         (char*)d_ws, wb, sf, stream);
    } else {
        for (int b = 0; b < 4; ++b)
            run_pipeline(1, x + (size_t)b * LSEQ * DM,
                         (float*)d_out + (size_t)b * LSEQ * DM,
                         (char*)d_ws, wb, sf, stream);
    }
}

// Round 5
// 1200.304 us; speedup vs baseline: 1.0698x; 1.0698x over previous
//
#include <hip/hip_runtime.h>
#include <cstdint>

typedef unsigned short u16;
typedef unsigned int u32;
typedef __bf16 bf16x8 __attribute__((ext_vector_type(8)));
typedef float f32x4 __attribute__((ext_vector_type(4)));
typedef unsigned short u16x8 __attribute__((ext_vector_type(8)));
typedef unsigned short u16x4 __attribute__((ext_vector_type(4)));

#define BM 128
#define BN 128
#define BK 32    // per-plane K depth; main loop processes 2 planes (K=64) per barrier pair
#define PL (BM * BK)   // plane stride in elements (4096)
#define CL 16     // scan chunk length
#define NC 256    // chunks per channel (CL*NC = 4096 = L)
#define DI 2048   // d_inner
#define DM 1024   // d_model
#define LSEQ 4096

__device__ __forceinline__ float bf2f(u16 u) {
    union { uint32_t i; float f; } v; v.i = ((uint32_t)u) << 16; return v.f;
}
__device__ __forceinline__ u16 f2bf(float f) {
    union { float f; uint32_t i; } v; v.f = f;
    uint32_t r = v.i + 0x7fffu + ((v.i >> 16) & 1u);
    return (u16)(r >> 16);
}

// async global->LDS, 16B per lane; LDS dst = base + lane*16 (wave-uniform base)
__device__ __forceinline__ void gl_lds16(const u16* g, u16* l) {
    __builtin_amdgcn_global_load_lds(
        (const __attribute__((address_space(1))) u32*)g,
        (__attribute__((address_space(3))) u32*)l, 16, 0, 0);
}

// ---------------------------------------------------------------------------
// f32 -> bf16 cast (vectorized x8)
// ---------------------------------------------------------------------------
__global__ __launch_bounds__(256)
void cast_f2b(const float* __restrict__ src, u16* __restrict__ dst, long n)
{
    long i = ((long)blockIdx.x * 256 + threadIdx.x) * 8;
    if (i >= n) return;
    float4 v0 = *(const float4*)(src + i);
    float4 v1 = *(const float4*)(src + i + 4);
    u16x8 o;
    o[0] = f2bf(v0.x); o[1] = f2bf(v0.y); o[2] = f2bf(v0.z); o[3] = f2bf(v0.w);
    o[4] = f2bf(v1.x); o[5] = f2bf(v1.y); o[6] = f2bf(v1.z); o[7] = f2bf(v1.w);
    *(u16x8*)(dst + i) = o;
}

// all 5 weight casts in one launch (segments are multiples of 8 elements)
__global__ __launch_bounds__(256)
void cast_weights(const float* __restrict__ Wi, const float* __restrict__ Wdt,
                  const float* __restrict__ WB, const float* __restrict__ WC,
                  const float* __restrict__ Wo,
                  u16* __restrict__ Wi_b, u16* __restrict__ Wcat_b,
                  u16* __restrict__ Wo_b)
{
    const long nWi = (long)2 * DI * DM;
    const long nWp = (long)DI * DI;
    long i = ((long)blockIdx.x * 256 + threadIdx.x) * 8;
    const float* src; u16* dst; long off;
    if (i < nWi)                  { src = Wi;  dst = Wi_b;            off = i; }
    else if (i < nWi + nWp)       { src = Wdt; dst = Wcat_b;          off = i - nWi; }
    else if (i < nWi + 2 * nWp)   { src = WB;  dst = Wcat_b + nWp;    off = i - nWi - nWp; }
    else if (i < nWi + 3 * nWp)   { src = WC;  dst = Wcat_b + 2*nWp;  off = i - nWi - 2*nWp; }
    else                          { src = Wo;  dst = Wo_b;            off = i - nWi - 3*nWp; }
    float4 v0 = *(const float4*)(src + off);
    float4 v1 = *(const float4*)(src + off + 4);
    u16x8 o;
    o[0] = f2bf(v0.x); o[1] = f2bf(v0.y); o[2] = f2bf(v0.z); o[3] = f2bf(v0.w);
    o[4] = f2bf(v1.x); o[5] = f2bf(v1.y); o[6] = f2bf(v1.z); o[7] = f2bf(v1.w);
    *(u16x8*)(dst + off) = o;
}

// ---------------------------------------------------------------------------
// GEMM (m97-style, K-unrolled x2): C[M,N] = A[M,K] * W[N,K]^T, bf16, fp32 acc.
// LDS: two independent 32-col planes per matrix. Each iteration stages K=64
// (8 x global_load_lds) then 32 MFMA per wave.
// Staging swizzle: row r holds global 16B-chunk c at slot (c + (r>>1)) & 3.
// NOTE (R3): XCD block swizzle REGRESSED (FETCH 366->768 MB) — the default
// n-fastest mapping pins n-tile columns to XCD n%8 (gridDim.x % 8 == 0),
// keeping W slices L2-resident. Do not swizzle.
// R5: dbc split into three N=2048 kernels (dt/u/ct) so rocprof's top-5
// decomposes the pipeline — dbc's 6 instances were masking everything <310us.
// EPI 0: in_proj  N=4096, split -> x1(ob0), z(ob1)          [bf16]
// EPI 2: out_proj N=1024 -> f32 (outf)
// EPI 3: dt  = softplus(v + bdt)                            [bf16]
// EPI 4: u   = sigmoid(v) * xc(auxb)                        [bf16]
// EPI 5: Ct  = tanh(v)                                      [bf16]
// ---------------------------------------------------------------------------
template<int EPI>
__device__ __forceinline__ void gemm_body(
             const u16* __restrict__ A, const u16* __restrict__ W, int K,
             const float* __restrict__ auxf, const u16* __restrict__ auxb,
             u16* __restrict__ ob0, u16* __restrict__ ob1,
             float* __restrict__ outf)
{
    __shared__ __align__(16) u16 As[2 * BM * BK];   // 16 KB: two planes
    __shared__ __align__(16) u16 Bs[2 * BN * BK];   // 16 KB

    const int t    = threadIdx.x;
    const int lane = t & 63;
    const int w    = t >> 6;
    const int quad = lane >> 4;
    const int l16  = lane & 15;
    const int wm   = w >> 1, wn = w & 1;
    const long m0  = (long)blockIdx.y * BM;
    const long n0  = (long)blockIdx.x * BN;

    // ---- staging lane constants ----
    // inst q covers rows q*16..q*16+15; lane i -> row q*16 + (i>>2), slot i&3
    // global chunk for this slot: cg = ((i&3) - ((i>>3)&3)) & 3
    const int rr = lane >> 2;
    const int cg = ((lane & 3) - ((lane >> 3) & 3)) & 3;

    const u16* gA0 = A + (size_t)(m0 + (2 * w)     * 16 + rr) * K + cg * 8;
    const u16* gA1 = A + (size_t)(m0 + (2 * w + 1) * 16 + rr) * K + cg * 8;
    const u16* gB0 = W + (size_t)(n0 + (2 * w)     * 16 + rr) * K + cg * 8;
    const u16* gB1 = W + (size_t)(n0 + (2 * w + 1) * 16 + rr) * K + cg * 8;

    u16* lA0 = As + (2 * w)     * 512;
    u16* lA1 = As + (2 * w + 1) * 512;
    u16* lB0 = Bs + (2 * w)     * 512;
    u16* lB1 = Bs + (2 * w + 1) * 512;

    // ---- fragment read constants ----
    const int slotr = (quad + (l16 >> 1)) & 3;
    const u16* rdA = As + (wm * 64 + l16) * 32 + slotr * 8;
    const u16* rdB = Bs + (wn * 64 + l16) * 32 + slotr * 8;

    f32x4 acc[4][4];
#pragma unroll
    for (int i = 0; i < 4; ++i)
#pragma unroll
        for (int j = 0; j < 4; ++j)
            acc[i][j] = (f32x4){0.f, 0.f, 0.f, 0.f};

    for (int k0 = 0; k0 < K; k0 += 2 * BK) {
        __syncthreads();                    // prev-iter LDS reads done
        gl_lds16(gA0 + k0, lA0);
        gl_lds16(gA1 + k0, lA1);
        gl_lds16(gA0 + k0 + BK, lA0 + PL);
        gl_lds16(gA1 + k0 + BK, lA1 + PL);
        gl_lds16(gB0 + k0, lB0);
        gl_lds16(gB1 + k0, lB1);
        gl_lds16(gB0 + k0 + BK, lB0 + PL);
        gl_lds16(gB1 + k0 + BK, lB1 + PL);
        __syncthreads();                    // DMA drained

#pragma unroll
        for (int kk = 0; kk < 2; ++kk) {
            const u16* pA = rdA + kk * PL;
            const u16* pB = rdB + kk * PL;
            bf16x8 af[4], bfr[4];
#pragma unroll
            for (int fi = 0; fi < 4; ++fi)
                af[fi] = *(const bf16x8*)(pA + fi * 512);
#pragma unroll
            for (int fj = 0; fj < 4; ++fj)
                bfr[fj] = *(const bf16x8*)(pB + fj * 512);
#pragma unroll
            for (int i = 0; i < 4; ++i)
#pragma unroll
                for (int j = 0; j < 4; ++j)
                    acc[i][j] = __builtin_amdgcn_mfma_f32_16x16x32_bf16(af[i], bfr[j], acc[i][j], 0, 0, 0);
        }
    }

    // epilogue: C/D layout col=lane&15, row=quad*4+reg  [m89/m91-verified]
#pragma unroll
    for (int i = 0; i < 4; ++i) {
#pragma unroll
        for (int j = 0; j < 4; ++j) {
            const long nc = n0 + wn * 64 + j * 16 + l16;
#pragma unroll
            for (int rg = 0; rg < 4; ++rg) {
                const long mr = m0 + wm * 64 + i * 16 + quad * 4 + rg;
                float v = acc[i][j][rg];
                if (EPI == 0) {
                    if (nc < DI) ob0[mr * DI + nc] = f2bf(v);
                    else         ob1[mr * DI + (nc - DI)] = f2bf(v);
                } else if (EPI == 2) {
                    outf[mr * DM + nc] = v;
                } else if (EPI == 3) {
                    float vv = v + auxf[nc];
                    float sp = (vv > 20.f) ? vv : log1pf(expf(vv));
                    ob0[mr * DI + nc] = f2bf(sp);
                } else if (EPI == 4) {
                    float bt  = 1.f / (1.f + expf(-v));
                    float xcv = bf2f(auxb[mr * DI + nc]);
                    ob0[mr * DI + nc] = f2bf(xcv * bt);
                } else if (EPI == 5) {
                    ob0[mr * DI + nc] = f2bf(tanhf(v));
                }
            }
        }
    }
}

// distinct names so rocprof's top-5 decomposes the pipeline
__global__ __launch_bounds__(256, 4)
void gemm_in(const u16* __restrict__ A, const u16* __restrict__ W, int K,
             u16* __restrict__ ob0, u16* __restrict__ ob1)
{
    gemm_body<0>(A, W, K, nullptr, nullptr, ob0, ob1, nullptr);
}
__global__ __launch_bounds__(256, 4)
void gemm_dt(const u16* __restrict__ A, const u16* __restrict__ W, int K,
             const float* __restrict__ bdt, u16* __restrict__ ob0)
{
    gemm_body<3>(A, W, K, bdt, nullptr, ob0, nullptr, nullptr);
}
__global__ __launch_bounds__(256, 4)
void gemm_u(const u16* __restrict__ A, const u16* __restrict__ W, int K,
            const u16* __restrict__ xc, u16* __restrict__ ob0)
{
    gemm_body<4>(A, W, K, nullptr, xc, ob0, nullptr, nullptr);
}
__global__ __launch_bounds__(256, 4)
void gemm_ct(const u16* __restrict__ A, const u16* __restrict__ W, int K,
             u16* __restrict__ ob0)
{
    gemm_body<5>(A, W, K, nullptr, nullptr, ob0, nullptr, nullptr);
}
__global__ __launch_bounds__(256, 4)
void gemm_out(const u16* __restrict__ A, const u16* __restrict__ W, int K,
              float* __restrict__ outf)
{
    gemm_body<2>(A, W, K, nullptr, nullptr, nullptr, nullptr, outf);
}

// ---------------------------------------------------------------------------
// depthwise causal conv1d (k=4) + bias + silu : x1[nb,L,D](bf16) -> xc (bf16)
// one block per (b,l) row; 256 threads x 8 channels = DI; 16B row loads
// ---------------------------------------------------------------------------
__global__ __launch_bounds__(256)
void conv_silu(const u16* __restrict__ x1, const float* __restrict__ Wc,
               const float* __restrict__ bc, u16* __restrict__ xc)
{
    const long bl = blockIdx.x;             // b*L + l
    const int  l  = (int)(bl & (LSEQ - 1));
    const int  d0 = threadIdx.x * 8;
    const size_t base = (size_t)bl * DI + d0;

    float acc[8];
    {
        float4 b0 = *(const float4*)(bc + d0);
        float4 b1 = *(const float4*)(bc + d0 + 4);
        acc[0] = b0.x; acc[1] = b0.y; acc[2] = b0.z; acc[3] = b0.w;
        acc[4] = b1.x; acc[5] = b1.y; acc[6] = b1.z; acc[7] = b1.w;
    }
    float wv[8][4];
#pragma unroll
    for (int v = 0; v < 8; ++v) {
        float4 t = *(const float4*)(Wc + (size_t)(d0 + v) * 4);
        wv[v][0] = t.x; wv[v][1] = t.y; wv[v][2] = t.z; wv[v][3] = t.w;
    }

#pragma unroll
    for (int tp = 0; tp < 4; ++tp) {
        const int ls = l - 3 + tp;          // uniform per block
        if (ls >= 0) {
            u16x8 vx = *(const u16x8*)(x1 + base + (long)(tp - 3) * DI);
#pragma unroll
            for (int v = 0; v < 8; ++v)
                acc[v] += bf2f(vx[v]) * wv[v][tp];
        }
    }
    u16x8 o;
#pragma unroll
    for (int v = 0; v < 8; ++v) {
        float s = acc[v] / (1.f + expf(-acc[v]));   // silu
        o[v] = f2bf(s);
    }
    *(u16x8*)(xc + base) = o;
}

// ---------------------------------------------------------------------------
// scan (h_l = exp(la_l)*h_{l-1} + beta_l), chunked 3-pass.
// 4 channels/thread, grid (2, nb, NC) = 2048 blocks, prefetch depth 2.
// NOTE: prefetch may read up to 32B past a big buffer's end (into the next
// allocated buffer) on the trailing chunks — value discarded, always in-ws.
// ---------------------------------------------------------------------------
__global__ __launch_bounds__(256)
void scan_a(const u16* __restrict__ dt, const u16* __restrict__ u,
            const float* __restrict__ A_log,
            float* __restrict__ sumlog, float* __restrict__ hend, int nbD)
{
    const int d0 = (blockIdx.x * 256 + threadIdx.x) * 4;   // 2*256*4 = DI
    const int b  = blockIdx.y;
    const int c  = blockIdx.z;
    float Ad[4];
    {
        float4 a = *(const float4*)(A_log + d0);
        Ad[0] = -expf(a.x); Ad[1] = -expf(a.y); Ad[2] = -expf(a.z); Ad[3] = -expf(a.w);
    }
    size_t base = ((size_t)b * LSEQ + (size_t)c * CL) * DI + d0;

    float pu[4], sl[4], h[4];
    if (c == 0) {
#pragma unroll
        for (int v = 0; v < 4; ++v) pu[v] = 0.f;
    } else {
        u16x4 vp = *(const u16x4*)(u + base - DI);
#pragma unroll
        for (int v = 0; v < 4; ++v) pu[v] = bf2f(vp[v]);
    }
#pragma unroll
    for (int v = 0; v < 4; ++v) { sl[v] = 0.f; h[v] = 0.f; }

    u16x4 d_0 = *(const u16x4*)(dt + base);
    u16x4 u_0 = *(const u16x4*)(u  + base);
    u16x4 d_1 = *(const u16x4*)(dt + base + DI);
    u16x4 u_1 = *(const u16x4*)(u  + base + DI);
    for (int s = 0; s < CL; ++s) {
        u16x4 d_2 = *(const u16x4*)(dt + base + 2 * DI);
        u16x4 u_2 = *(const u16x4*)(u  + base + 2 * DI);
#pragma unroll
        for (int v = 0; v < 4; ++v) {
            float dtv = bf2f(d_0[v]);
            float uv  = bf2f(u_0[v]);
            float la  = fminf(fmaxf(Ad[v] * dtv, -10.f), -1e-4f);
            sl[v] += la;
            h[v] = expf(la) * h[v] + dtv * 0.5f * (pu[v] + uv);
            pu[v] = uv;
        }
        d_0 = d_1; u_0 = u_1; d_1 = d_2; u_1 = u_2;
        base += DI;
    }
    const size_t chn = (size_t)c * nbD + b * DI + d0;
    *(float4*)(sumlog + chn) = (float4){sl[0], sl[1], sl[2], sl[3]};
    *(float4*)(hend   + chn) = (float4){h[0], h[1], h[2], h[3]};
}

// 128-thread blocks (64 blocks for nbD=8192); unroll-by-8 with hoisted loads
// and batched exp so the load latency is paid NC/8 times, not NC.
__global__ __launch_bounds__(128)
void scan_b(const float* __restrict__ sumlog, const float* __restrict__ hend,
            float* __restrict__ hin, int nbD)
{
    const int chn = blockIdx.x * 128 + threadIdx.x;   // 0..nbD-1
    float carry = 0.f;
    for (int c0 = 0; c0 < NC; c0 += 8) {
        float sl[8], he[8];
#pragma unroll
        for (int k = 0; k < 8; ++k) {
            sl[k] = sumlog[(size_t)(c0 + k) * nbD + chn];
            he[k] = hend  [(size_t)(c0 + k) * nbD + chn];
        }
        float e[8];
#pragma unroll
        for (int k = 0; k < 8; ++k) e[k] = expf(sl[k]);
#pragma unroll
        for (int k = 0; k < 8; ++k) {
            hin[(size_t)(c0 + k) * nbD + chn] = carry;
            carry = e[k] * carry + he[k];
        }
    }
}

__global__ __launch_bounds__(256)
void scan_c(const u16* __restrict__ dt, const u16* __restrict__ u,
            const float* __restrict__ A_log, const float* __restrict__ hin,
            const u16* __restrict__ Ct, const u16* __restrict__ z,
            u16* __restrict__ y, int nbD)
{
    const int d0 = (blockIdx.x * 256 + threadIdx.x) * 4;
    const int b  = blockIdx.y;
    const int c  = blockIdx.z;
    float Ad[4];
    {
        float4 a = *(const float4*)(A_log + d0);
        Ad[0] = -expf(a.x); Ad[1] = -expf(a.y); Ad[2] = -expf(a.z); Ad[3] = -expf(a.w);
    }
    size_t base = ((size_t)b * LSEQ + (size_t)c * CL) * DI + d0;
    const size_t chn = (size_t)c * nbD + b * DI + d0;

    float h[4], pu[4];
    {
        float4 h4 = *(const float4*)(hin + chn);
        h[0] = h4.x; h[1] = h4.y; h[2] = h4.z; h[3] = h4.w;
    }
    if (c == 0) {
#pragma unroll
        for (int v = 0; v < 4; ++v) pu[v] = 0.f;
    } else {
        u16x4 vp = *(const u16x4*)(u + base - DI);
#pragma unroll
        for (int v = 0; v < 4; ++v) pu[v] = bf2f(vp[v]);
    }

    u16x4 d_0 = *(const u16x4*)(dt + base);
    u16x4 u_0 = *(const u16x4*)(u  + base);
    u16x4 c_0 = *(const u16x4*)(Ct + base);
    u16x4 z_0 = *(const u16x4*)(z  + base);
    u16x4 d_1 = *(const u16x4*)(dt + base + DI);
    u16x4 u_1 = *(const u16x4*)(u  + base + DI);
    u16x4 c_1 = *(const u16x4*)(Ct + base + DI);
    u16x4 z_1 = *(const u16x4*)(z  + base + DI);
    for (int s = 0; s < CL; ++s) {
        u16x4 d_2 = *(const u16x4*)(dt + base + 2 * DI);
        u16x4 u_2 = *(const u16x4*)(u  + base + 2 * DI);
        u16x4 c_2 = *(const u16x4*)(Ct + base + 2 * DI);
        u16x4 z_2 = *(const u16x4*)(z  + base + 2 * DI);
        u16x4 o;
#pragma unroll
        for (int v = 0; v < 4; ++v) {
            float dtv = bf2f(d_0[v]);
            float uv  = bf2f(u_0[v]);
            float la  = fminf(fmaxf(Ad[v] * dtv, -10.f), -1e-4f);
            h[v] = expf(la) * h[v] + dtv * 0.5f * (pu[v] + uv);
            pu[v] = uv;
            float ct = bf2f(c_0[v]);
            float zv = bf2f(z_0[v]);
            float sz = zv / (1.f + expf(-zv));   // silu(z)
            o[v] = f2bf(h[v] * ct * sz);
        }
        *(u16x4*)(y + base) = o;
        d_0 = d_1; u_0 = u_1; c_0 = c_1; z_0 = z_1;
        d_1 = d_2; u_1 = u_2; c_1 = c_2; z_1 = z_2;
        base += DI;
    }
}

// ---------------------------------------------------------------------------
struct WeightsB {   // bf16 casts of the big weights (in ws)
    const u16 *Wi, *Wcat, *Wo;   // Wcat = [Wdt; WB; WC], 6144 x 2048
};
struct SmallF {     // small f32 inputs consumed directly
    const float *Wconv, *bconv, *bdt, *A_log;
};

static void run_pipeline(int nb, const float* x, float* out, char* ws,
                         const WeightsB& wb, const SmallF& sf, hipStream_t stream)
{
    const int Mrows = nb * LSEQ;
    const size_t nE = (size_t)Mrows * DI;    // elements per big buffer
    const size_t nX = (size_t)Mrows * DM;
    const int nbD = nb * DI;
    const size_t nWp = (size_t)DI * DI;

    char* p = ws;
    u16* b0 = (u16*)p; p += nE * 2;   // x1, then dt
    u16* b1 = (u16*)p; p += nE * 2;   // z
    u16* b2 = (u16*)p; p += nE * 2;   // xc  (first half doubles as xb; scan
                                      //      smalls live here after the proj GEMMs)
    u16* b3 = (u16*)p; p += nE * 2;   // u
    u16* b4 = (u16*)p; p += nE * 2;   // Ct, then y (in-place in scan_c)

    u16* xb = b2;                       // x cast; dead before conv writes xc
    u16* x1 = b0; u16* z = b1; u16* xc = b2;
    u16* dt = b0; u16* u  = b3; u16* Ct = b4; u16* y = b4;

    // scan chunk summaries: xc/b2 is dead after gemm_ct consumes it
    // (3 * nbD * NC * 4 bytes = 25 MB @ nb=4  <<  nE*2 = 67 MB)
    float* sumlog = (float*)b2;
    float* hend   = sumlog + (size_t)nbD * NC;
    float* hin    = hend   + (size_t)nbD * NC;

    dim3 blk(256);

    // 0) cast activations input (into xc's buffer — released before conv)
    cast_f2b<<<dim3((unsigned)(nX / 2048)), blk, 0, stream>>>(x, xb, (long)nX);

    // 1) in_proj: xz = x @ Wi^T -> (x1, z)
    gemm_in<<<dim3(2 * DI / BN, Mrows / BM), blk, 0, stream>>>(
        xb, wb.Wi, DM, x1, z);

    // 2) causal depthwise conv + silu (overwrites xb region)
    conv_silu<<<dim3((unsigned)Mrows), blk, 0, stream>>>(x1, sf.Wconv, sf.bconv, xc);

    // 3) dt/B/C projections as three N=2048 GEMMs (R5 split: decomposes the
    //    profile; math identical to the former fused N=6144 gemm_dbc)
    gemm_dt<<<dim3(DI / BN, Mrows / BM), blk, 0, stream>>>(
        xc, wb.Wcat, DI, sf.bdt, dt);
    gemm_u<<<dim3(DI / BN, Mrows / BM), blk, 0, stream>>>(
        xc, wb.Wcat + nWp, DI, xc, u);
    gemm_ct<<<dim3(DI / BN, Mrows / BM), blk, 0, stream>>>(
        xc, wb.Wcat + 2 * nWp, DI, Ct);

    // 4) chunked scan + fuse y = h * Ct * silu(z); y overwrites Ct in-place
    scan_a<<<dim3(2, nb, NC), blk, 0, stream>>>(dt, u, sf.A_log, sumlog, hend, nbD);
    scan_b<<<dim3(nbD / 128), dim3(128), 0, stream>>>(sumlog, hend, hin, nbD);
    scan_c<<<dim3(2, nb, NC), blk, 0, stream>>>(dt, u, sf.A_log, hin, Ct, z, y, nbD);

    // 5) out_proj -> out (f32)
    gemm_out<<<dim3(DM / BN, Mrows / BM), blk, 0, stream>>>(
        y, wb.Wo, DI, out);
}

extern "C" void kernel_launch(void* const* d_in, const int* in_sizes, int n_in,
                              void* d_out, int out_size, void* d_ws, size_t ws_size,
                              hipStream_t stream)
{
    const float* x     = (const float*)d_in[0];
    const float* Wi    = (const float*)d_in[1];
    const float* Wconv = (const float*)d_in[2];
    const float* bconv = (const float*)d_in[3];
    const float* Wdt   = (const float*)d_in[4];
    const float* bdt   = (const float*)d_in[5];
    const float* WB    = (const float*)d_in[6];
    const float* WC    = (const float*)d_in[7];
    const float* Wo    = (const float*)d_in[8];
    const float* A_log = (const float*)d_in[9];

    const size_t nWi = (size_t)2 * DI * DM;   // 4.19M
    const size_t nWp = (size_t)DI * DI;       // 4.19M
    const size_t nWo = (size_t)DM * DI;       // 2.10M

    // weight casts live at the END of ws (shared by all paths)
    const size_t wbytes = (nWi + 3 * nWp + nWo) * 2;
    char* q = (char*)d_ws + ws_size - wbytes;
    u16* Wi_b   = (u16*)q; q += nWi * 2;
    u16* Wcat_b = (u16*)q; q += 3 * nWp * 2;   // [Wdt; WB; WC]
    u16* Wo_b   = (u16*)q; q += nWo * 2;

    dim3 blk(256);
    {
        const long nW = (long)(nWi + 3 * nWp + nWo);   // 18.9M, /8/256 = 9216 blocks
        cast_weights<<<dim3((unsigned)(nW / 2048)), blk, 0, stream>>>(
            Wi, Wdt, WB, WC, Wo, Wi_b, Wcat_b, Wo_b);
    }

    WeightsB wb{Wi_b, Wcat_b, Wo_b};
    SmallF   sf{Wconv, bconv, bdt, A_log};

    // big-buffer need for nb batches (xb and scan smalls aliased into xc):
    auto need = [&](int nb) -> size_t {
        size_t nE = (size_t)nb * LSEQ * DI;
        return 5 * nE * 2;
    };

    if (ws_size >= need(4) + wbytes) {
        run_pipeline(4, x, (float*)d_out, (char*)d_ws, wb, sf, stream);
    } else if (ws_size >= need(2) + wbytes) {
        for (int b = 0; b < 4; b += 2)
            run_pipeline(2, x + (size_t)b * LSEQ * DM,
                         (float*)d_out + (size_t)b * LSEQ * DM,
                         (char*)d_ws, wb, sf, stream);
    } else {
        for (int b = 0; b < 4; ++b)
            run_pipeline(1, x + (size_t)b * LSEQ * DM,
                         (float*)d_out + (size_t)b * LSEQ * DM,
                         (char*)d_ws, wb, sf, stream);
    }
}

// Round 6
// 1102.760 us; speedup vs baseline: 1.1645x; 1.0885x over previous
//
#include <hip/hip_runtime.h>
#include <cstdint>

typedef unsigned short u16;
typedef unsigned int u32;
typedef __bf16 bf16x8 __attribute__((ext_vector_type(8)));
typedef float f32x4 __attribute__((ext_vector_type(4)));
typedef unsigned short u16x8 __attribute__((ext_vector_type(8)));
typedef unsigned short u16x4 __attribute__((ext_vector_type(4)));

#define BM 128
#define BN 128
#define BK 32    // per-plane K depth; main loop processes 2 planes (K=64) per barrier pair
#define PL (BM * BK)   // plane stride in elements (4096)
#define CL 16     // scan chunk length
#define NC 256    // chunks per channel (CL*NC = 4096 = L)
#define DI 2048   // d_inner
#define DM 1024   // d_model
#define LSEQ 4096

__device__ __forceinline__ float bf2f(u16 u) {
    union { uint32_t i; float f; } v; v.i = ((uint32_t)u) << 16; return v.f;
}
__device__ __forceinline__ u16 f2bf(float f) {
    union { float f; uint32_t i; } v; v.f = f;
    uint32_t r = v.i + 0x7fffu + ((v.i >> 16) & 1u);
    return (u16)(r >> 16);
}

// ---- fast transcendentals (v_exp_f32 / v_log_f32 hardware ops) ----
// R5 PMC: libm log1pf/expf/tanhf epilogues ~2900 VALU instrs/thread made
// gemm_dt VALUBusy 58% / MfmaUtil 23%. Fast forms are ~10x cheaper; rel
// error ~2^-21 << bf16 quantization (2^-8).
__device__ __forceinline__ float fsoftplus(float x) {
    return (x > 20.f) ? x : __logf(1.f + __expf(x));
}
__device__ __forceinline__ float fsigmoid(float x) {
    return __fdividef(1.f, 1.f + __expf(-x));
}
__device__ __forceinline__ float fsilu(float x) {
    return __fdividef(x, 1.f + __expf(-x));
}
__device__ __forceinline__ float ftanh(float x) {
    float e = __expf(-2.f * fabsf(x));          // |x| large -> e=0 -> t=1
    float t = __fdividef(1.f - e, 1.f + e);
    return copysignf(t, x);
}

// async global->LDS, 16B per lane; LDS dst = base + lane*16 (wave-uniform base)
__device__ __forceinline__ void gl_lds16(const u16* g, u16* l) {
    __builtin_amdgcn_global_load_lds(
        (const __attribute__((address_space(1))) u32*)g,
        (__attribute__((address_space(3))) u32*)l, 16, 0, 0);
}

// ---------------------------------------------------------------------------
// f32 -> bf16 cast (vectorized x8)
// ---------------------------------------------------------------------------
__global__ __launch_bounds__(256)
void cast_f2b(const float* __restrict__ src, u16* __restrict__ dst, long n)
{
    long i = ((long)blockIdx.x * 256 + threadIdx.x) * 8;
    if (i >= n) return;
    float4 v0 = *(const float4*)(src + i);
    float4 v1 = *(const float4*)(src + i + 4);
    u16x8 o;
    o[0] = f2bf(v0.x); o[1] = f2bf(v0.y); o[2] = f2bf(v0.z); o[3] = f2bf(v0.w);
    o[4] = f2bf(v1.x); o[5] = f2bf(v1.y); o[6] = f2bf(v1.z); o[7] = f2bf(v1.w);
    *(u16x8*)(dst + i) = o;
}

// all 5 weight casts in one launch (segments are multiples of 8 elements)
__global__ __launch_bounds__(256)
void cast_weights(const float* __restrict__ Wi, const float* __restrict__ Wdt,
                  const float* __restrict__ WB, const float* __restrict__ WC,
                  const float* __restrict__ Wo,
                  u16* __restrict__ Wi_b, u16* __restrict__ Wcat_b,
                  u16* __restrict__ Wo_b)
{
    const long nWi = (long)2 * DI * DM;
    const long nWp = (long)DI * DI;
    long i = ((long)blockIdx.x * 256 + threadIdx.x) * 8;
    const float* src; u16* dst; long off;
    if (i < nWi)                  { src = Wi;  dst = Wi_b;            off = i; }
    else if (i < nWi + nWp)       { src = Wdt; dst = Wcat_b;          off = i - nWi; }
    else if (i < nWi + 2 * nWp)   { src = WB;  dst = Wcat_b + nWp;    off = i - nWi - nWp; }
    else if (i < nWi + 3 * nWp)   { src = WC;  dst = Wcat_b + 2*nWp;  off = i - nWi - 2*nWp; }
    else                          { src = Wo;  dst = Wo_b;            off = i - nWi - 3*nWp; }
    float4 v0 = *(const float4*)(src + off);
    float4 v1 = *(const float4*)(src + off + 4);
    u16x8 o;
    o[0] = f2bf(v0.x); o[1] = f2bf(v0.y); o[2] = f2bf(v0.z); o[3] = f2bf(v0.w);
    o[4] = f2bf(v1.x); o[5] = f2bf(v1.y); o[6] = f2bf(v1.z); o[7] = f2bf(v1.w);
    *(u16x8*)(dst + off) = o;
}

// ---------------------------------------------------------------------------
// GEMM (m97-style, K-unrolled x2): C[M,N] = A[M,K] * W[N,K]^T, bf16, fp32 acc.
// LDS: two independent 32-col planes per matrix. Each iteration stages K=64
// (8 x global_load_lds) then 32 MFMA per wave.
// Staging swizzle: row r holds global 16B-chunk c at slot (c + (r>>1)) & 3.
// NOTE (R3): XCD block swizzle REGRESSED (FETCH 366->768 MB) — default
// n-fastest mapping keeps W slices L2-resident. Do not swizzle.
// EPI 0: in_proj  N=4096, split -> x1(ob0), z(ob1)          [bf16]
// EPI 2: out_proj N=1024 -> f32 (outf)
// EPI 3: dt  = softplus(v + bdt)                            [bf16]
// EPI 4: u   = sigmoid(v) * xc(auxb)                        [bf16]
// EPI 5: Ct  = tanh(v)                                      [bf16]
// ---------------------------------------------------------------------------
template<int EPI>
__device__ __forceinline__ void gemm_body(
             const u16* __restrict__ A, const u16* __restrict__ W, int K,
             const float* __restrict__ auxf, const u16* __restrict__ auxb,
             u16* __restrict__ ob0, u16* __restrict__ ob1,
             float* __restrict__ outf)
{
    __shared__ __align__(16) u16 As[2 * BM * BK];   // 16 KB: two planes
    __shared__ __align__(16) u16 Bs[2 * BN * BK];   // 16 KB

    const int t    = threadIdx.x;
    const int lane = t & 63;
    const int w    = t >> 6;
    const int quad = lane >> 4;
    const int l16  = lane & 15;
    const int wm   = w >> 1, wn = w & 1;
    const long m0  = (long)blockIdx.y * BM;
    const long n0  = (long)blockIdx.x * BN;

    // ---- staging lane constants ----
    // inst q covers rows q*16..q*16+15; lane i -> row q*16 + (i>>2), slot i&3
    // global chunk for this slot: cg = ((i&3) - ((i>>3)&3)) & 3
    const int rr = lane >> 2;
    const int cg = ((lane & 3) - ((lane >> 3) & 3)) & 3;

    const u16* gA0 = A + (size_t)(m0 + (2 * w)     * 16 + rr) * K + cg * 8;
    const u16* gA1 = A + (size_t)(m0 + (2 * w + 1) * 16 + rr) * K + cg * 8;
    const u16* gB0 = W + (size_t)(n0 + (2 * w)     * 16 + rr) * K + cg * 8;
    const u16* gB1 = W + (size_t)(n0 + (2 * w + 1) * 16 + rr) * K + cg * 8;

    u16* lA0 = As + (2 * w)     * 512;
    u16* lA1 = As + (2 * w + 1) * 512;
    u16* lB0 = Bs + (2 * w)     * 512;
    u16* lB1 = Bs + (2 * w + 1) * 512;

    // ---- fragment read constants ----
    const int slotr = (quad + (l16 >> 1)) & 3;
    const u16* rdA = As + (wm * 64 + l16) * 32 + slotr * 8;
    const u16* rdB = Bs + (wn * 64 + l16) * 32 + slotr * 8;

    f32x4 acc[4][4];
#pragma unroll
    for (int i = 0; i < 4; ++i)
#pragma unroll
        for (int j = 0; j < 4; ++j)
            acc[i][j] = (f32x4){0.f, 0.f, 0.f, 0.f};

    for (int k0 = 0; k0 < K; k0 += 2 * BK) {
        __syncthreads();                    // prev-iter LDS reads done
        gl_lds16(gA0 + k0, lA0);
        gl_lds16(gA1 + k0, lA1);
        gl_lds16(gA0 + k0 + BK, lA0 + PL);
        gl_lds16(gA1 + k0 + BK, lA1 + PL);
        gl_lds16(gB0 + k0, lB0);
        gl_lds16(gB1 + k0, lB1);
        gl_lds16(gB0 + k0 + BK, lB0 + PL);
        gl_lds16(gB1 + k0 + BK, lB1 + PL);
        __syncthreads();                    // DMA drained

#pragma unroll
        for (int kk = 0; kk < 2; ++kk) {
            const u16* pA = rdA + kk * PL;
            const u16* pB = rdB + kk * PL;
            bf16x8 af[4], bfr[4];
#pragma unroll
            for (int fi = 0; fi < 4; ++fi)
                af[fi] = *(const bf16x8*)(pA + fi * 512);
#pragma unroll
            for (int fj = 0; fj < 4; ++fj)
                bfr[fj] = *(const bf16x8*)(pB + fj * 512);
#pragma unroll
            for (int i = 0; i < 4; ++i)
#pragma unroll
                for (int j = 0; j < 4; ++j)
                    acc[i][j] = __builtin_amdgcn_mfma_f32_16x16x32_bf16(af[i], bfr[j], acc[i][j], 0, 0, 0);
        }
    }

    // epilogue: C/D layout col=lane&15, row=quad*4+reg  [m89/m91-verified]
#pragma unroll
    for (int i = 0; i < 4; ++i) {
#pragma unroll
        for (int j = 0; j < 4; ++j) {
            const long nc = n0 + wn * 64 + j * 16 + l16;
#pragma unroll
            for (int rg = 0; rg < 4; ++rg) {
                const long mr = m0 + wm * 64 + i * 16 + quad * 4 + rg;
                float v = acc[i][j][rg];
                if (EPI == 0) {
                    if (nc < DI) ob0[mr * DI + nc] = f2bf(v);
                    else         ob1[mr * DI + (nc - DI)] = f2bf(v);
                } else if (EPI == 2) {
                    outf[mr * DM + nc] = v;
                } else if (EPI == 3) {
                    ob0[mr * DI + nc] = f2bf(fsoftplus(v + auxf[nc]));
                } else if (EPI == 4) {
                    float xcv = bf2f(auxb[mr * DI + nc]);
                    ob0[mr * DI + nc] = f2bf(xcv * fsigmoid(v));
                } else if (EPI == 5) {
                    ob0[mr * DI + nc] = f2bf(ftanh(v));
                }
            }
        }
    }
}

// distinct names so rocprof's top-5 decomposes the pipeline
__global__ __launch_bounds__(256, 4)
void gemm_in(const u16* __restrict__ A, const u16* __restrict__ W, int K,
             u16* __restrict__ ob0, u16* __restrict__ ob1)
{
    gemm_body<0>(A, W, K, nullptr, nullptr, ob0, ob1, nullptr);
}
__global__ __launch_bounds__(256, 4)
void gemm_dt(const u16* __restrict__ A, const u16* __restrict__ W, int K,
             const float* __restrict__ bdt, u16* __restrict__ ob0)
{
    gemm_body<3>(A, W, K, bdt, nullptr, ob0, nullptr, nullptr);
}
__global__ __launch_bounds__(256, 4)
void gemm_u(const u16* __restrict__ A, const u16* __restrict__ W, int K,
            const u16* __restrict__ xc, u16* __restrict__ ob0)
{
    gemm_body<4>(A, W, K, nullptr, xc, ob0, nullptr, nullptr);
}
__global__ __launch_bounds__(256, 4)
void gemm_ct(const u16* __restrict__ A, const u16* __restrict__ W, int K,
             u16* __restrict__ ob0)
{
    gemm_body<5>(A, W, K, nullptr, nullptr, ob0, nullptr, nullptr);
}
__global__ __launch_bounds__(256, 4)
void gemm_out(const u16* __restrict__ A, const u16* __restrict__ W, int K,
              float* __restrict__ outf)
{
    gemm_body<2>(A, W, K, nullptr, nullptr, nullptr, nullptr, outf);
}

// ---------------------------------------------------------------------------
// depthwise causal conv1d (k=4) + bias + silu : x1[nb,L,D](bf16) -> xc (bf16)
// one block per (b,l) row; 256 threads x 8 channels = DI; 16B row loads
// ---------------------------------------------------------------------------
__global__ __launch_bounds__(256)
void conv_silu(const u16* __restrict__ x1, const float* __restrict__ Wc,
               const float* __restrict__ bc, u16* __restrict__ xc)
{
    const long bl = blockIdx.x;             // b*L + l
    const int  l  = (int)(bl & (LSEQ - 1));
    const int  d0 = threadIdx.x * 8;
    const size_t base = (size_t)bl * DI + d0;

    float acc[8];
    {
        float4 b0 = *(const float4*)(bc + d0);
        float4 b1 = *(const float4*)(bc + d0 + 4);
        acc[0] = b0.x; acc[1] = b0.y; acc[2] = b0.z; acc[3] = b0.w;
        acc[4] = b1.x; acc[5] = b1.y; acc[6] = b1.z; acc[7] = b1.w;
    }
    float wv[8][4];
#pragma unroll
    for (int v = 0; v < 8; ++v) {
        float4 t = *(const float4*)(Wc + (size_t)(d0 + v) * 4);
        wv[v][0] = t.x; wv[v][1] = t.y; wv[v][2] = t.z; wv[v][3] = t.w;
    }

#pragma unroll
    for (int tp = 0; tp < 4; ++tp) {
        const int ls = l - 3 + tp;          // uniform per block
        if (ls >= 0) {
            u16x8 vx = *(const u16x8*)(x1 + base + (long)(tp - 3) * DI);
#pragma unroll
            for (int v = 0; v < 8; ++v)
                acc[v] += bf2f(vx[v]) * wv[v][tp];
        }
    }
    u16x8 o;
#pragma unroll
    for (int v = 0; v < 8; ++v)
        o[v] = f2bf(fsilu(acc[v]));
    *(u16x8*)(xc + base) = o;
}

// ---------------------------------------------------------------------------
// scan (h_l = exp(la_l)*h_{l-1} + beta_l), chunked 3-pass.
// 4 channels/thread, grid (2, nb, NC) = 2048 blocks, prefetch depth 2.
// NOTE: prefetch may read up to 32B past a big buffer's end (into the next
// allocated buffer) on the trailing chunks — value discarded, always in-ws.
// ---------------------------------------------------------------------------
__global__ __launch_bounds__(256)
void scan_a(const u16* __restrict__ dt, const u16* __restrict__ u,
            const float* __restrict__ A_log,
            float* __restrict__ sumlog, float* __restrict__ hend, int nbD)
{
    const int d0 = (blockIdx.x * 256 + threadIdx.x) * 4;   // 2*256*4 = DI
    const int b  = blockIdx.y;
    const int c  = blockIdx.z;
    float Ad[4];
    {
        float4 a = *(const float4*)(A_log + d0);
        Ad[0] = -__expf(a.x); Ad[1] = -__expf(a.y); Ad[2] = -__expf(a.z); Ad[3] = -__expf(a.w);
    }
    size_t base = ((size_t)b * LSEQ + (size_t)c * CL) * DI + d0;

    float pu[4], sl[4], h[4];
    if (c == 0) {
#pragma unroll
        for (int v = 0; v < 4; ++v) pu[v] = 0.f;
    } else {
        u16x4 vp = *(const u16x4*)(u + base - DI);
#pragma unroll
        for (int v = 0; v < 4; ++v) pu[v] = bf2f(vp[v]);
    }
#pragma unroll
    for (int v = 0; v < 4; ++v) { sl[v] = 0.f; h[v] = 0.f; }

    u16x4 d_0 = *(const u16x4*)(dt + base);
    u16x4 u_0 = *(const u16x4*)(u  + base);
    u16x4 d_1 = *(const u16x4*)(dt + base + DI);
    u16x4 u_1 = *(const u16x4*)(u  + base + DI);
    for (int s = 0; s < CL; ++s) {
        u16x4 d_2 = *(const u16x4*)(dt + base + 2 * DI);
        u16x4 u_2 = *(const u16x4*)(u  + base + 2 * DI);
#pragma unroll
        for (int v = 0; v < 4; ++v) {
            float dtv = bf2f(d_0[v]);
            float uv  = bf2f(u_0[v]);
            float la  = fminf(fmaxf(Ad[v] * dtv, -10.f), -1e-4f);
            sl[v] += la;
            h[v] = __expf(la) * h[v] + dtv * 0.5f * (pu[v] + uv);
            pu[v] = uv;
        }
        d_0 = d_1; u_0 = u_1; d_1 = d_2; u_1 = u_2;
        base += DI;
    }
    const size_t chn = (size_t)c * nbD + b * DI + d0;
    *(float4*)(sumlog + chn) = (float4){sl[0], sl[1], sl[2], sl[3]};
    *(float4*)(hend   + chn) = (float4){h[0], h[1], h[2], h[3]};
}

// 128-thread blocks (64 blocks for nbD=8192); unroll-by-8 with hoisted loads
// and batched exp so the load latency is paid NC/8 times, not NC.
__global__ __launch_bounds__(128)
void scan_b(const float* __restrict__ sumlog, const float* __restrict__ hend,
            float* __restrict__ hin, int nbD)
{
    const int chn = blockIdx.x * 128 + threadIdx.x;   // 0..nbD-1
    float carry = 0.f;
    for (int c0 = 0; c0 < NC; c0 += 8) {
        float sl[8], he[8];
#pragma unroll
        for (int k = 0; k < 8; ++k) {
            sl[k] = sumlog[(size_t)(c0 + k) * nbD + chn];
            he[k] = hend  [(size_t)(c0 + k) * nbD + chn];
        }
        float e[8];
#pragma unroll
        for (int k = 0; k < 8; ++k) e[k] = __expf(sl[k]);
#pragma unroll
        for (int k = 0; k < 8; ++k) {
            hin[(size_t)(c0 + k) * nbD + chn] = carry;
            carry = e[k] * carry + he[k];
        }
    }
}

__global__ __launch_bounds__(256)
void scan_c(const u16* __restrict__ dt, const u16* __restrict__ u,
            const float* __restrict__ A_log, const float* __restrict__ hin,
            const u16* __restrict__ Ct, const u16* __restrict__ z,
            u16* __restrict__ y, int nbD)
{
    const int d0 = (blockIdx.x * 256 + threadIdx.x) * 4;
    const int b  = blockIdx.y;
    const int c  = blockIdx.z;
    float Ad[4];
    {
        float4 a = *(const float4*)(A_log + d0);
        Ad[0] = -__expf(a.x); Ad[1] = -__expf(a.y); Ad[2] = -__expf(a.z); Ad[3] = -__expf(a.w);
    }
    size_t base = ((size_t)b * LSEQ + (size_t)c * CL) * DI + d0;
    const size_t chn = (size_t)c * nbD + b * DI + d0;

    float h[4], pu[4];
    {
        float4 h4 = *(const float4*)(hin + chn);
        h[0] = h4.x; h[1] = h4.y; h[2] = h4.z; h[3] = h4.w;
    }
    if (c == 0) {
#pragma unroll
        for (int v = 0; v < 4; ++v) pu[v] = 0.f;
    } else {
        u16x4 vp = *(const u16x4*)(u + base - DI);
#pragma unroll
        for (int v = 0; v < 4; ++v) pu[v] = bf2f(vp[v]);
    }

    u16x4 d_0 = *(const u16x4*)(dt + base);
    u16x4 u_0 = *(const u16x4*)(u  + base);
    u16x4 c_0 = *(const u16x4*)(Ct + base);
    u16x4 z_0 = *(const u16x4*)(z  + base);
    u16x4 d_1 = *(const u16x4*)(dt + base + DI);
    u16x4 u_1 = *(const u16x4*)(u  + base + DI);
    u16x4 c_1 = *(const u16x4*)(Ct + base + DI);
    u16x4 z_1 = *(const u16x4*)(z  + base + DI);
    for (int s = 0; s < CL; ++s) {
        u16x4 d_2 = *(const u16x4*)(dt + base + 2 * DI);
        u16x4 u_2 = *(const u16x4*)(u  + base + 2 * DI);
        u16x4 c_2 = *(const u16x4*)(Ct + base + 2 * DI);
        u16x4 z_2 = *(const u16x4*)(z  + base + 2 * DI);
        u16x4 o;
#pragma unroll
        for (int v = 0; v < 4; ++v) {
            float dtv = bf2f(d_0[v]);
            float uv  = bf2f(u_0[v]);
            float la  = fminf(fmaxf(Ad[v] * dtv, -10.f), -1e-4f);
            h[v] = __expf(la) * h[v] + dtv * 0.5f * (pu[v] + uv);
            pu[v] = uv;
            float ct = bf2f(c_0[v]);
            float zv = bf2f(z_0[v]);
            o[v] = f2bf(h[v] * ct * fsilu(zv));
        }
        *(u16x4*)(y + base) = o;
        d_0 = d_1; u_0 = u_1; c_0 = c_1; z_0 = z_1;
        d_1 = d_2; u_1 = u_2; c_1 = c_2; z_1 = z_2;
        base += DI;
    }
}

// ---------------------------------------------------------------------------
struct WeightsB {   // bf16 casts of the big weights (in ws)
    const u16 *Wi, *Wcat, *Wo;   // Wcat = [Wdt; WB; WC], 6144 x 2048
};
struct SmallF {     // small f32 inputs consumed directly
    const float *Wconv, *bconv, *bdt, *A_log;
};

static void run_pipeline(int nb, const float* x, float* out, char* ws,
                         const WeightsB& wb, const SmallF& sf, hipStream_t stream)
{
    const int Mrows = nb * LSEQ;
    const size_t nE = (size_t)Mrows * DI;    // elements per big buffer
    const size_t nX = (size_t)Mrows * DM;
    const int nbD = nb * DI;
    const size_t nWp = (size_t)DI * DI;

    char* p = ws;
    u16* b0 = (u16*)p; p += nE * 2;   // x1, then dt
    u16* b1 = (u16*)p; p += nE * 2;   // z
    u16* b2 = (u16*)p; p += nE * 2;   // xc  (first half doubles as xb; scan
                                      //      smalls live here after the proj GEMMs)
    u16* b3 = (u16*)p; p += nE * 2;   // u
    u16* b4 = (u16*)p; p += nE * 2;   // Ct, then y (in-place in scan_c)

    u16* xb = b2;                       // x cast; dead before conv writes xc
    u16* x1 = b0; u16* z = b1; u16* xc = b2;
    u16* dt = b0; u16* u  = b3; u16* Ct = b4; u16* y = b4;

    // scan chunk summaries: xc/b2 is dead after gemm_ct consumes it
    // (3 * nbD * NC * 4 bytes = 25 MB @ nb=4  <<  nE*2 = 67 MB)
    float* sumlog = (float*)b2;
    float* hend   = sumlog + (size_t)nbD * NC;
    float* hin    = hend   + (size_t)nbD * NC;

    dim3 blk(256);

    // 0) cast activations input (into xc's buffer — released before conv)
    cast_f2b<<<dim3((unsigned)(nX / 2048)), blk, 0, stream>>>(x, xb, (long)nX);

    // 1) in_proj: xz = x @ Wi^T -> (x1, z)
    gemm_in<<<dim3(2 * DI / BN, Mrows / BM), blk, 0, stream>>>(
        xb, wb.Wi, DM, x1, z);

    // 2) causal depthwise conv + silu (overwrites xb region)
    conv_silu<<<dim3((unsigned)Mrows), blk, 0, stream>>>(x1, sf.Wconv, sf.bconv, xc);

    // 3) dt/B/C projections as three N=2048 GEMMs (R5 split: decomposes the
    //    profile; math identical to the former fused N=6144 gemm_dbc)
    gemm_dt<<<dim3(DI / BN, Mrows / BM), blk, 0, stream>>>(
        xc, wb.Wcat, DI, sf.bdt, dt);
    gemm_u<<<dim3(DI / BN, Mrows / BM), blk, 0, stream>>>(
        xc, wb.Wcat + nWp, DI, xc, u);
    gemm_ct<<<dim3(DI / BN, Mrows / BM), blk, 0, stream>>>(
        xc, wb.Wcat + 2 * nWp, DI, Ct);

    // 4) chunked scan + fuse y = h * Ct * silu(z); y overwrites Ct in-place
    scan_a<<<dim3(2, nb, NC), blk, 0, stream>>>(dt, u, sf.A_log, sumlog, hend, nbD);
    scan_b<<<dim3(nbD / 128), dim3(128), 0, stream>>>(sumlog, hend, hin, nbD);
    scan_c<<<dim3(2, nb, NC), blk, 0, stream>>>(dt, u, sf.A_log, hin, Ct, z, y, nbD);

    // 5) out_proj -> out (f32)
    gemm_out<<<dim3(DM / BN, Mrows / BM), blk, 0, stream>>>(
        y, wb.Wo, DI, out);
}

extern "C" void kernel_launch(void* const* d_in, const int* in_sizes, int n_in,
                              void* d_out, int out_size, void* d_ws, size_t ws_size,
                              hipStream_t stream)
{
    const float* x     = (const float*)d_in[0];
    const float* Wi    = (const float*)d_in[1];
    const float* Wconv = (const float*)d_in[2];
    const float* bconv = (const float*)d_in[3];
    const float* Wdt   = (const float*)d_in[4];
    const float* bdt   = (const float*)d_in[5];
    const float* WB    = (const float*)d_in[6];
    const float* WC    = (const float*)d_in[7];
    const float* Wo    = (const float*)d_in[8];
    const float* A_log = (const float*)d_in[9];

    const size_t nWi = (size_t)2 * DI * DM;   // 4.19M
    const size_t nWp = (size_t)DI * DI;       // 4.19M
    const size_t nWo = (size_t)DM * DI;       // 2.10M

    // weight casts live at the END of ws (shared by all paths)
    const size_t wbytes = (nWi + 3 * nWp + nWo) * 2;
    char* q = (char*)d_ws + ws_size - wbytes;
    u16* Wi_b   = (u16*)q; q += nWi * 2;
    u16* Wcat_b = (u16*)q; q += 3 * nWp * 2;   // [Wdt; WB; WC]
    u16* Wo_b   = (u16*)q; q += nWo * 2;

    dim3 blk(256);
    {
        const long nW = (long)(nWi + 3 * nWp + nWo);   // 18.9M, /8/256 = 9216 blocks
        cast_weights<<<dim3((unsigned)(nW / 2048)), blk, 0, stream>>>(
            Wi, Wdt, WB, WC, Wo, Wi_b, Wcat_b, Wo_b);
    }

    WeightsB wb{Wi_b, Wcat_b, Wo_b};
    SmallF   sf{Wconv, bconv, bdt, A_log};

    // big-buffer need for nb batches (xb and scan smalls aliased into xc):
    auto need = [&](int nb) -> size_t {
        size_t nE = (size_t)nb * LSEQ * DI;
        return 5 * nE * 2;
    };

    if (ws_size >= need(4) + wbytes) {
        run_pipeline(4, x, (float*)d_out, (char*)d_ws, wb, sf, stream);
    } else if (ws_size >= need(2) + wbytes) {
        for (int b = 0; b < 4; b += 2)
            run_pipeline(2, x + (size_t)b * LSEQ * DM,
                         (float*)d_out + (size_t)b * LSEQ * DM,
                         (char*)d_ws, wb, sf, stream);
    } else {
        for (int b = 0; b < 4; ++b)
            run_pipeline(1, x + (size_t)b * LSEQ * DM,
                         (float*)d_out + (size_t)b * LSEQ * DM,
                         (char*)d_ws, wb, sf, stream);
    }
}